// Round 6
// baseline (226.814 us; speedup 1.0000x reference)
//
#include <hip/hip_runtime.h>
#include <hip/hip_bf16.h>

typedef float f32x4 __attribute__((ext_vector_type(4)));
typedef __bf16 bf16x8 __attribute__((ext_vector_type(8)));

static constexpr int S  = 2048;
static constexpr int D  = 1024;
static constexpr int DK = 64;
static constexpr int KDIM = 1024;
// 0.125 (1/sqrt(dk)) * log2(e): folded into Q so QK^T lands in exp2 domain
static constexpr float QSCALE = 0.18033688f;

#define AS1 __attribute__((address_space(1)))
#define AS3 __attribute__((address_space(3)))

__device__ __forceinline__ void glds16(const void* g, void* l) {
  __builtin_amdgcn_global_load_lds((const AS1 void*)g, (AS3 void*)l, 16, 0, 0);
}

__device__ __forceinline__ unsigned cvtpk(float lo, float hi) {
  unsigned r;
  asm("v_cvt_pk_bf16_f32 %0, %1, %2" : "=v"(r) : "v"(lo), "v"(hi));
  return r;
}

__device__ __forceinline__ void pl32swap(unsigned& a, unsigned& b) {
  asm("v_permlane32_swap_b32 %0, %1" : "+v"(a), "+v"(b));
}

__device__ __forceinline__ float fexp2(float x) {
  float r;
  asm("v_exp_f32 %0, %1" : "=v"(r) : "v"(x));
  return r;
}

// k-permutation within a 64 block (bijective); maps r=0..3 (k aligned 4) to
// consecutive outputs, enabling vectorized V^T stores.
__device__ __forceinline__ int kperm64(int k) {
  const int kf = k >> 4, hs = (k >> 2) & 3, r = k & 3;
  const bool inl = ((kf & 1) == (hs >> 1));
  const int h = inl ? hs : (hs ^ 2);
  const int j = inl ? r : (r + 4);
  return ((kf >> 1) << 5) + (h << 3) + j;
}

// ---------------- fused pre-pass: all f32->bf16 cvt + RoPE tables ----------
__global__ __launch_bounds__(256) void pre_kernel(
    const float* __restrict__ x,  const float* __restrict__ Wq,
    const float* __restrict__ Wk, const float* __restrict__ Wv,
    const float* __restrict__ Wo,
    __hip_bfloat16* __restrict__ xb, __hip_bfloat16* __restrict__ Wcat,
    __hip_bfloat16* __restrict__ Wob,
    float* __restrict__ cosT, float* __restrict__ sinT) {
  const int gid = blockIdx.x * 256 + threadIdx.x;
  if (gid < 2097152) {
    const float* src;
    __hip_bfloat16* dst;
    int off;
    if (gid < 1048576)      { src = x;  dst = xb;             off = gid; }
    else if (gid < 1310720) { src = Wq; dst = Wcat;           off = gid - 1048576; }
    else if (gid < 1572864) { src = Wk; dst = Wcat + 1048576; off = gid - 1310720; }
    else if (gid < 1835008) { src = Wv; dst = Wcat + 2097152; off = gid - 1572864; }
    else                    { src = Wo; dst = Wob;            off = gid - 1835008; }
    float4 v = reinterpret_cast<const float4*>(src)[off];
    union { ushort4 u; __hip_bfloat16 h[4]; } o;
    o.h[0] = __float2bfloat16(v.x);
    o.h[1] = __float2bfloat16(v.y);
    o.h[2] = __float2bfloat16(v.z);
    o.h[3] = __float2bfloat16(v.w);
    reinterpret_cast<ushort4*>(dst)[off] = o.u;
  } else {
    const int idx = gid - 2097152;  // S*32
    const int s = idx >> 5, fi = idx & 31;
    float invf = powf(10000.0f, -(float)(2 * fi) / 64.0f);
    float ang = (float)s * invf;
    cosT[idx] = cosf(ang);
    sinT[idx] = sinf(ang);
  }
}

// ---------------- NT GEMM v2: chunk-major LDS + dbuf, BM x BN tile --------
// LDS layout per buffer: [A: c*BM+row][16B] then [B: c*BN+row][16B] --
// fragment ds_read_b128 becomes conflict-free (consecutive rows per group).
// 2-phase: stage tile k+1, compute tile k, one barrier per iteration.
template <int MODE, int BM, int BN>
__global__ __launch_bounds__(256) void gemm_nt_kernel(
    const __hip_bfloat16* __restrict__ A,
    const __hip_bfloat16* __restrict__ Bw,
    float* __restrict__ Cf,
    __hip_bfloat16* __restrict__ Qr,
    __hip_bfloat16* __restrict__ Kr,
    __hip_bfloat16* __restrict__ Vt,
    const float* __restrict__ cosT,
    const float* __restrict__ sinT,
    int Ncols) {
  constexpr int ACH = BM * 4;        // 16B chunks per K-tile (BK=32) for A
  constexpr int BCH = BN * 4;
  constexpr int TCH = ACH + BCH;
  constexpr int NI = (BM == 128) ? 4 : 2;  // n-frags per wave
  __shared__ __attribute__((aligned(16))) char smem[2][TCH * 16];
  const int tid = threadIdx.x;
  const int nbn = Ncols / BN;
  const int cpx = gridDim.x >> 3;
  const int swz = (blockIdx.x & 7) * cpx + (blockIdx.x >> 3);
  const int bm = swz / nbn;
  const int bn = swz % nbn;
  const int m0 = bm * BM, n0 = bn * BN;
  const int lane = tid & 63;
  const int wid = tid >> 6;
  const int r16 = lane & 15, hf = lane >> 4;
  const int wmoff = (BM == 128) ? ((wid >> 1) << 6) : 0;
  const int wnoff = (BM == 128) ? ((wid & 1) << 6) : (wid << 5);

  f32x4 acc[4][NI];
#pragma unroll
  for (int i = 0; i < 4; ++i)
#pragma unroll
    for (int j = 0; j < NI; ++j) acc[i][j] = (f32x4)0.0f;

  auto stage = [&](int bufi, int k0) {
#pragma unroll
    for (int i = 0; i < TCH / 256; ++i) {
      const int idx = i * 256 + tid;
      char* dst = &smem[bufi][idx * 16];
      if (idx < ACH) {
        const int row = idx % BM, c = idx / BM;
        glds16((const char*)A + ((size_t)(m0 + row) * KDIM + k0) * 2 + c * 16,
               dst);
      } else {
        const int bi = idx - ACH;
        const int row = bi % BN, c = bi / BN;
        glds16((const char*)Bw + ((size_t)(n0 + row) * KDIM + k0) * 2 + c * 16,
               dst);
      }
    }
  };

  stage(0, 0);
  __syncthreads();

  for (int kb = 0; kb < KDIM / 32; ++kb) {
    const int cur = kb & 1;
    if (kb + 1 < KDIM / 32) stage(cur ^ 1, (kb + 1) * 32);

    const char* Ab = smem[cur];
    const char* Bb = smem[cur] + ACH * 16;
    bf16x8 af[4], bfr[NI];
#pragma unroll
    for (int mi = 0; mi < 4; ++mi)
      af[mi] = *(const bf16x8*)(Ab + (hf * BM + wmoff + mi * 16 + r16) * 16);
#pragma unroll
    for (int ni = 0; ni < NI; ++ni)
      bfr[ni] = *(const bf16x8*)(Bb + (hf * BN + wnoff + ni * 16 + r16) * 16);
#pragma unroll
    for (int mi = 0; mi < 4; ++mi)
#pragma unroll
      for (int ni = 0; ni < NI; ++ni)
        acc[mi][ni] = __builtin_amdgcn_mfma_f32_16x16x32_bf16(af[mi], bfr[ni],
                                                              acc[mi][ni], 0, 0, 0);
    __syncthreads();
  }

  if constexpr (MODE == 0) {
#pragma unroll
    for (int mi = 0; mi < 4; ++mi) {
      const int rowb = m0 + wmoff + (mi << 4) + (hf << 2);
#pragma unroll
      for (int ni = 0; ni < NI; ++ni) {
        const int col = n0 + wnoff + (ni << 4) + r16;
#pragma unroll
        for (int r = 0; r < 4; ++r)
          Cf[(size_t)(rowb + r) * Ncols + col] = acc[mi][ni][r];
      }
    }
  } else {
    const int proj = n0 >> 10;
#pragma unroll
    for (int mi = 0; mi < 4; ++mi) {
      const int rowb = m0 + wmoff + (mi << 4) + (hf << 2);
      const int b = rowb >> 11;  // uniform for r=0..3 (rowb % 4 == 0)
      const int sbase = rowb & 2047;
#pragma unroll
      for (int ni = 0; ni < NI; ++ni) {
        const int col = n0 + wnoff + (ni << 4) + r16;
        const int ecol = col & 1023;
        const int h = ecol >> 6, dk = ecol & 63;
        if (proj < 2) {
#pragma unroll
          for (int r = 0; r < 4; ++r) {
            float v = acc[mi][ni][r];
            const int s = sbase + r;
            float p = __shfl_xor(v, 1, 64);
            const int fi = dk >> 1;
            const float c = cosT[(s << 5) + fi];
            const float sn = sinT[(s << 5) + fi];
            float ov = v * c + ((dk & 1) ? p : -p) * sn;
            if (proj == 0) ov *= QSCALE;  // fold 1/sqrt(dk)*log2e into Q
            __hip_bfloat16* dst = (proj == 0) ? Qr : Kr;
            dst[((size_t)((b << 4) + h) * S + s) * DK + dk] = __float2bfloat16(ov);
          }
        } else {
          // V: k-permuted store; r=0..3 map to consecutive sp -> ushort4
          const int sp0 = (sbase & ~63) | kperm64(sbase & 63);
          union { ushort4 u; __hip_bfloat16 hh[4]; } vp;
#pragma unroll
          for (int r = 0; r < 4; ++r)
            vp.hh[r] = __float2bfloat16(acc[mi][ni][r]);
          *reinterpret_cast<ushort4*>(
              &Vt[((size_t)((b << 4) + h) * DK + dk) * S + sp0]) = vp.u;
        }
      }
    }
  }
}

// ---------------- causal flash attention v5 (balanced triples) ------------
__global__ __launch_bounds__(256) void attn_kernel(
    const __hip_bfloat16* __restrict__ Q,
    const __hip_bfloat16* __restrict__ Kr,
    const __hip_bfloat16* __restrict__ Vp,
    __hip_bfloat16* __restrict__ AO,
    __hip_bfloat16* __restrict__ Opart,  // [bh][16 splits][128][64] bf16
    float* __restrict__ ml) {            // [bh][16 splits][128][2] f32
  __shared__ __attribute__((aligned(16))) __hip_bfloat16 Ks[2][64 * 64];
  __shared__ __attribute__((aligned(16))) __hip_bfloat16 Vs[2][64 * 64];
  static const int T[8][3] = {{0, 1, 23},  {2, 5, 20},  {3, 9, 17}, {4, 15, 14},
                              {6, 16, 21}, {7, 11, 18}, {10, 8, 22}, {12, 13, 19}};
  const int tid = threadIdx.x;
  const int lane = tid & 63, wid = tid >> 6;
  const int r16 = lane & 15, hf = lane >> 4;
  const bool hi32 = (lane >= 32);
  const int bh = blockIdx.x & 31;
  const int cg = (blockIdx.x >> 5) & 7;
  const int slot = blockIdx.x >> 8;
  const int item = T[cg][slot];
  const int g = item / 3, j = item - 3 * g;
  int qt, k0, k1;
  bool dosplit;
  if (j < 2) {
    qt = 15 - g;
    const int nt = (qt << 1) + 2;
    k0 = j ? (nt >> 1) : 0;
    k1 = j ? nt : (nt >> 1);
    dosplit = true;
  } else {
    qt = 7 - g;
    k0 = 0;
    k1 = (qt << 1) + 2;
    dosplit = false;
  }
  const __hip_bfloat16* Qh = Q + (size_t)bh * S * DK;
  const __hip_bfloat16* Kh = Kr + (size_t)bh * S * DK;
  const __hip_bfloat16* Vh = Vp + (size_t)bh * DK * S;

  const int qbase = (qt << 7) + (wid << 5);

  bf16x8 bq[2][2];
#pragma unroll
  for (int qf = 0; qf < 2; ++qf)
#pragma unroll
    for (int ks = 0; ks < 2; ++ks)
      bq[qf][ks] = *(const bf16x8*)(Qh + (size_t)(qbase + (qf << 4) + r16) * DK +
                                    ks * 32 + hf * 8);

  f32x4 o[2][4];
#pragma unroll
  for (int qf = 0; qf < 2; ++qf)
#pragma unroll
    for (int f = 0; f < 4; ++f) o[qf][f] = (f32x4)0.0f;
  float m[2] = {-1e30f, -1e30f}, l[2] = {0.0f, 0.0f};

#define STAGE(bufi, t)                                                         \
  {                                                                            \
    _Pragma("unroll") for (int i = 0; i < 2; ++i) {                            \
      const int idx = i * 256 + tid;                                           \
      const int row = idx >> 3;                                                \
      const int cb = (idx & 7) << 4;                                           \
      const int scb = cb ^ ((row & 7) << 4);                                   \
      glds16((const char*)Kh + ((size_t)(((t) << 6) + row) * DK) * 2 + scb,    \
             (char*)(&Ks[bufi][0]) + idx * 16);                                \
      glds16((const char*)Vh + ((size_t)row * S + ((t) << 6)) * 2 + scb,       \
             (char*)(&Vs[bufi][0]) + idx * 16);                                \
    }                                                                          \
  }

  STAGE(0, k0);
  __syncthreads();

  for (int kt = k0; kt < k1; ++kt) {
    const int cur = (kt - k0) & 1;
    if (kt + 1 < k1) STAGE(cur ^ 1, kt + 1);

    // S^T = K Q^T  (scores already in exp2 domain via pre-scaled Q)
    f32x4 p[2][4];
#pragma unroll
    for (int qf = 0; qf < 2; ++qf)
#pragma unroll
      for (int kf = 0; kf < 4; ++kf) p[qf][kf] = (f32x4)0.0f;
    __builtin_amdgcn_s_setprio(1);
#pragma unroll
    for (int ks = 0; ks < 2; ++ks) {
#pragma unroll
      for (int kf = 0; kf < 4; ++kf) {
        const int krow = (kf << 4) + r16;
        const int cb = (ks << 6) + (hf << 4);
        const bf16x8 ak = *(const bf16x8*)((const char*)(&Ks[cur][0]) +
                                           krow * 128 + (cb ^ ((krow & 7) << 4)));
#pragma unroll
        for (int qf = 0; qf < 2; ++qf)
          p[qf][kf] = __builtin_amdgcn_mfma_f32_16x16x32_bf16(ak, bq[qf][ks],
                                                              p[qf][kf], 0, 0, 0);
      }
    }
    __builtin_amdgcn_s_setprio(0);

    // causal mask (diag tiles only; wave-uniform branch)
    if (kt >= (qt << 1)) {
#pragma unroll
      for (int qf = 0; qf < 2; ++qf) {
        const int qg = qbase + (qf << 4) + r16;
#pragma unroll
        for (int kf = 0; kf < 4; ++kf)
#pragma unroll
          for (int r = 0; r < 4; ++r) {
            const int kg = (kt << 6) + (kf << 4) + (hf << 2) + r;
            if (kg > qg) p[qf][kf][r] = -1e30f;
          }
      }
    }

    // online softmax with defer-max (T13, THR=8 log2-units)
#pragma unroll
    for (int qf = 0; qf < 2; ++qf) {
      f32x4 m4;
#pragma unroll
      for (int e = 0; e < 4; ++e)
        m4[e] = fmaxf(fmaxf(p[qf][0][e], p[qf][1][e]),
                      fmaxf(p[qf][2][e], p[qf][3][e]));
      float t = fmaxf(fmaxf(m4[0], m4[1]), fmaxf(m4[2], m4[3]));
      t = fmaxf(t, __shfl_xor(t, 16, 64));
      t = fmaxf(t, __shfl_xor(t, 32, 64));
      if (t > m[qf] + 8.0f) {  // wave-uniform
        const float scl = fexp2(m[qf] - t);
        m[qf] = t;
        l[qf] *= scl;
#pragma unroll
        for (int f = 0; f < 4; ++f)
#pragma unroll
          for (int r = 0; r < 4; ++r) o[qf][f][r] *= scl;
      }
      float ss = 0.0f;
#pragma unroll
      for (int kf = 0; kf < 4; ++kf)
#pragma unroll
        for (int r = 0; r < 4; ++r) {
          const float e = fexp2(p[qf][kf][r] - m[qf]);
          p[qf][kf][r] = e;
          ss += e;
        }
      ss += __shfl_xor(ss, 16, 64);
      ss += __shfl_xor(ss, 32, 64);
      l[qf] += ss;
    }

    // P -> bf16 frags in-register
    union PW { unsigned u[4]; bf16x8 v; };
    PW pb[2][2];
#pragma unroll
    for (int qf = 0; qf < 2; ++qf) {
      unsigned w[4][2];
#pragma unroll
      for (int kf = 0; kf < 4; ++kf) {
        w[kf][0] = cvtpk(p[qf][kf][0], p[qf][kf][1]);
        w[kf][1] = cvtpk(p[qf][kf][2], p[qf][kf][3]);
      }
#pragma unroll
      for (int ks = 0; ks < 2; ++ks) {
        unsigned a0 = w[2 * ks][0], b0 = w[2 * ks + 1][0];
        unsigned a1 = w[2 * ks][1], b1 = w[2 * ks + 1][1];
        pb[qf][ks].u[0] = hi32 ? b0 : a0;
        pb[qf][ks].u[1] = hi32 ? b1 : a1;
        pl32swap(a0, b0);
        pl32swap(a1, b1);
        pb[qf][ks].u[2] = hi32 ? a0 : b0;
        pb[qf][ks].u[3] = hi32 ? a1 : b1;
      }
    }

    // O^T += V' P
    __builtin_amdgcn_s_setprio(1);
#pragma unroll
    for (int ks = 0; ks < 2; ++ks) {
#pragma unroll
      for (int f = 0; f < 4; ++f) {
        const int vrow = (f << 4) + r16;
        const int cb = (ks << 6) + (hf << 4);
        const bf16x8 av = *(const bf16x8*)((const char*)(&Vs[cur][0]) +
                                           vrow * 128 + (cb ^ ((vrow & 7) << 4)));
#pragma unroll
        for (int qf = 0; qf < 2; ++qf)
          o[qf][f] = __builtin_amdgcn_mfma_f32_16x16x32_bf16(av, pb[qf][ks].v,
                                                             o[qf][f], 0, 0, 0);
      }
    }
    __builtin_amdgcn_s_setprio(0);

    __syncthreads();
  }
#undef STAGE

  if (!dosplit) {
    const int b = bh >> 4, h = bh & 15;
#pragma unroll
    for (int qf = 0; qf < 2; ++qf) {
      const float inv = 1.0f / l[qf];
      const int q = qbase + (qf << 4) + r16;
#pragma unroll
      for (int f = 0; f < 4; ++f)
#pragma unroll
        for (int r = 0; r < 4; ++r) {
          const int dv = (f << 4) + (hf << 2) + r;
          AO[((size_t)b * S + q) * D + (h << 6) + dv] =
              __float2bfloat16(o[qf][f][r] * inv);
        }
    }
  } else {
    const int sidx = (g << 1) | j;
    __hip_bfloat16* op = Opart + (((size_t)bh * 16 + sidx) << 13);
    float* mlp = ml + (((size_t)bh * 16 + sidx) << 8);
#pragma unroll
    for (int qf = 0; qf < 2; ++qf) {
      const float inv = 1.0f / l[qf];
      const int rowin = (wid << 5) + (qf << 4) + r16;
#pragma unroll
      for (int f = 0; f < 4; ++f)
#pragma unroll
        for (int r = 0; r < 4; ++r) {
          const int dv = (f << 4) + (hf << 2) + r;
          op[rowin * 64 + dv] = __float2bfloat16(o[qf][f][r] * inv);
        }
      if (hf == 0) {
        mlp[rowin * 2] = m[qf];
        mlp[rowin * 2 + 1] = l[qf];
      }
    }
  }
}

// ---------------- merge the split partials (m in exp2 domain) -------------
__global__ __launch_bounds__(256) void merge_kernel(
    const __hip_bfloat16* __restrict__ Opart,
    const float* __restrict__ ml,
    __hip_bfloat16* __restrict__ AO) {
  const int rg = blockIdx.x * 256 + threadIdx.x;  // 32768 rows
  const int bh = rg >> 10;
  const int rem = rg & 1023;
  const int gq = rem >> 7;  // 0..7 -> qt = 15-gq
  const int rowin = rem & 127;
  const int s0 = bh * 16 + (gq << 1), s1 = s0 + 1;
  const float m0 = ml[(s0 << 8) + rowin * 2], l0 = ml[(s0 << 8) + rowin * 2 + 1];
  const float m1 = ml[(s1 << 8) + rowin * 2], l1 = ml[(s1 << 8) + rowin * 2 + 1];
  const float mx = fmaxf(m0, m1);
  float w0 = l0 * fexp2(m0 - mx), w1 = l1 * fexp2(m1 - mx);
  const float inv = 1.0f / (w0 + w1);
  w0 *= inv;
  w1 *= inv;
  const bf16x8* p0 = (const bf16x8*)(Opart + (((size_t)s0) << 13) + rowin * 64);
  const bf16x8* p1 = (const bf16x8*)(Opart + (((size_t)s1) << 13) + rowin * 64);
  const int b = bh >> 4, h = bh & 15;
  const int q = ((15 - gq) << 7) + rowin;
  bf16x8* dst = (bf16x8*)(AO + ((size_t)b * S + q) * D + (h << 6));
#pragma unroll
  for (int i = 0; i < 8; ++i) {
    bf16x8 a = p0[i], c = p1[i];
    bf16x8 r;
#pragma unroll
    for (int e = 0; e < 8; ++e)
      r[e] = (__bf16)(w0 * (float)a[e] + w1 * (float)c[e]);
    dst[i] = r;
  }
}

extern "C" void kernel_launch(void* const* d_in, const int* in_sizes, int n_in,
                              void* d_out, int out_size, void* d_ws, size_t ws_size,
                              hipStream_t stream) {
  (void)in_sizes; (void)n_in; (void)out_size; (void)ws_size;
  const float* x  = (const float*)d_in[0];
  const float* Wq = (const float*)d_in[1];
  const float* Wk = (const float*)d_in[2];
  const float* Wv = (const float*)d_in[3];
  const float* Wo = (const float*)d_in[4];
  float* out = (float*)d_out;
  char* ws = (char*)d_ws;
  const size_t MB = (size_t)1 << 20;
  __hip_bfloat16* xb   = (__hip_bfloat16*)(ws);             //  8 MB (dead after gemm1)
  __hip_bfloat16* Wcat = (__hip_bfloat16*)(ws + 8 * MB);    //  6 MB (dead after gemm1)
  __hip_bfloat16* Wob  = (__hip_bfloat16*)(ws + 14 * MB);   //  2 MB (live till gemm0)
  __hip_bfloat16* Qr   = (__hip_bfloat16*)(ws + 16 * MB);   //  8 MB (pre-scaled)
  __hip_bfloat16* Kr   = (__hip_bfloat16*)(ws + 24 * MB);   //  8 MB
  __hip_bfloat16* Vt   = (__hip_bfloat16*)(ws + 32 * MB);   //  8 MB (k-permuted)
  __hip_bfloat16* AO   = (__hip_bfloat16*)(ws + 40 * MB);   //  8 MB
  float* cosT = (float*)(ws + 48 * MB);                     // 256 KB
  float* sinT = (float*)(ws + 48 * MB + 256 * 1024);        // 256 KB
  __hip_bfloat16* Opart = (__hip_bfloat16*)(ws);            //  8 MB (reuse xb)
  float* mlbuf = (float*)(ws + 8 * MB);                     //  512 KB (reuse Wcat)

  pre_kernel<<<8448, 256, 0, stream>>>(x, Wq, Wk, Wv, Wo, xb, Wcat, Wob,
                                       cosT, sinT);
  // QKV projection + RoPE + scatter: 128x128 tile, 768 blocks (3/CU)
  gemm_nt_kernel<1, 128, 128><<<(4096 / 128) * (3072 / 128), 256, 0, stream>>>(
      xb, Wcat, nullptr, Qr, Kr, Vt, cosT, sinT, 3072);
  attn_kernel<<<32 * 24, 256, 0, stream>>>(Qr, Kr, Vt, AO, Opart, mlbuf);
  merge_kernel<<<128, 256, 0, stream>>>(Opart, mlbuf, AO);
  // output projection: 64x128 tile, 512 blocks (2/CU)
  gemm_nt_kernel<0, 64, 128><<<(4096 / 64) * (1024 / 128), 256, 0, stream>>>(
      AO, Wob, out, nullptr, nullptr, nullptr, nullptr, nullptr, 1024);
}

// Round 7
// 191.189 us; speedup vs baseline: 1.1863x; 1.1863x over previous
//
#include <hip/hip_runtime.h>
#include <hip/hip_bf16.h>

typedef float f32x4 __attribute__((ext_vector_type(4)));
typedef __bf16 bf16x8 __attribute__((ext_vector_type(8)));

static constexpr int S  = 2048;
static constexpr int D  = 1024;
static constexpr int DK = 64;
static constexpr int KDIM = 1024;
// 0.125 (1/sqrt(dk)) * log2(e): folded into Q so QK^T lands in exp2 domain
static constexpr float QSCALE = 0.18033688f;

#define AS1 __attribute__((address_space(1)))
#define AS3 __attribute__((address_space(3)))

__device__ __forceinline__ void glds16(const void* g, void* l) {
  __builtin_amdgcn_global_load_lds((const AS1 void*)g, (AS3 void*)l, 16, 0, 0);
}

__device__ __forceinline__ unsigned cvtpk(float lo, float hi) {
  unsigned r;
  asm("v_cvt_pk_bf16_f32 %0, %1, %2" : "=v"(r) : "v"(lo), "v"(hi));
  return r;
}

__device__ __forceinline__ void pl32swap(unsigned& a, unsigned& b) {
  asm("v_permlane32_swap_b32 %0, %1" : "+v"(a), "+v"(b));
}

__device__ __forceinline__ float fexp2(float x) {
  float r;
  asm("v_exp_f32 %0, %1" : "=v"(r) : "v"(x));
  return r;
}

// k-permutation within a 64 block (bijective); maps r=0..3 (k aligned 4) to
// consecutive outputs, enabling vectorized V^T stores.
__device__ __forceinline__ int kperm64(int k) {
  const int kf = k >> 4, hs = (k >> 2) & 3, r = k & 3;
  const bool inl = ((kf & 1) == (hs >> 1));
  const int h = inl ? hs : (hs ^ 2);
  const int j = inl ? r : (r + 4);
  return ((kf >> 1) << 5) + (h << 3) + j;
}

// ---------------- fused pre-pass: all f32->bf16 cvt + RoPE tables ----------
__global__ __launch_bounds__(256) void pre_kernel(
    const float* __restrict__ x,  const float* __restrict__ Wq,
    const float* __restrict__ Wk, const float* __restrict__ Wv,
    const float* __restrict__ Wo,
    __hip_bfloat16* __restrict__ xb, __hip_bfloat16* __restrict__ Wcat,
    __hip_bfloat16* __restrict__ Wob,
    float* __restrict__ cosT, float* __restrict__ sinT) {
  const int gid = blockIdx.x * 256 + threadIdx.x;
  if (gid < 2097152) {
    const float* src;
    __hip_bfloat16* dst;
    int off;
    if (gid < 1048576)      { src = x;  dst = xb;             off = gid; }
    else if (gid < 1310720) { src = Wq; dst = Wcat;           off = gid - 1048576; }
    else if (gid < 1572864) { src = Wk; dst = Wcat + 1048576; off = gid - 1310720; }
    else if (gid < 1835008) { src = Wv; dst = Wcat + 2097152; off = gid - 1572864; }
    else                    { src = Wo; dst = Wob;            off = gid - 1835008; }
    float4 v = reinterpret_cast<const float4*>(src)[off];
    union { ushort4 u; __hip_bfloat16 h[4]; } o;
    o.h[0] = __float2bfloat16(v.x);
    o.h[1] = __float2bfloat16(v.y);
    o.h[2] = __float2bfloat16(v.z);
    o.h[3] = __float2bfloat16(v.w);
    reinterpret_cast<ushort4*>(dst)[off] = o.u;
  } else {
    const int idx = gid - 2097152;  // S*32
    const int s = idx >> 5, fi = idx & 31;
    float invf = powf(10000.0f, -(float)(2 * fi) / 64.0f);
    float ang = (float)s * invf;
    cosT[idx] = cosf(ang);
    sinT[idx] = sinf(ang);
  }
}

// ---------------- NT GEMM v3: row-major LDS + quad-swizzle + dbuf ---------
// LDS per buffer: A [BM rows][64B], B [BN rows][64B] (BK=32). The four 16B
// chunks of each 64B row are XOR-permuted by ((row>>1)&3) on BOTH the global
// source (stage) and the ds_read side (rule #21) -> ds_read_b128 fragments
// hit 8 distinct bank-quads at 2-way (free), staging stays fully coalesced
// (permutation is within each row's 64B). Single barrier per K-step.
template <int MODE, int BM, int BN>
__global__ __launch_bounds__(256) void gemm_nt_kernel(
    const __hip_bfloat16* __restrict__ A,
    const __hip_bfloat16* __restrict__ Bw,
    float* __restrict__ Cf,
    __hip_bfloat16* __restrict__ Qr,
    __hip_bfloat16* __restrict__ Kr,
    __hip_bfloat16* __restrict__ Vt,
    const float* __restrict__ cosT,
    const float* __restrict__ sinT,
    int Ncols) {
  constexpr int NI = (BM == 128) ? 4 : 2;  // n-frags per wave
  constexpr int ACH = BM * 4;              // 16B chunks in A tile
  constexpr int TCH = (BM + BN) * 4;
  __shared__ __attribute__((aligned(16))) char smem[2][(BM + BN) * 64];
  const int tid = threadIdx.x;
  const int nbn = Ncols / BN;
  const int cpx = gridDim.x >> 3;
  const int swz = (blockIdx.x & 7) * cpx + (blockIdx.x >> 3);
  const int bm = swz / nbn;
  const int bn = swz % nbn;
  const int m0 = bm * BM, n0 = bn * BN;
  const int lane = tid & 63;
  const int wid = tid >> 6;
  const int r16 = lane & 15, hf = lane >> 4;
  const int wmoff = (BM == 128) ? ((wid >> 1) << 6) : 0;
  const int wnoff = (BM == 128) ? ((wid & 1) << 6) : (wid << 5);
  const int gx = ((r16 >> 1) & 3) << 4;  // quad-swizzle for fragment reads

  f32x4 acc[4][NI];
#pragma unroll
  for (int i = 0; i < 4; ++i)
#pragma unroll
    for (int j = 0; j < NI; ++j) acc[i][j] = (f32x4)0.0f;

  auto stage = [&](int bufi, int k0) {
#pragma unroll
    for (int i = 0; i < TCH / 256; ++i) {
      const int idx = i * 256 + tid;
      char* dst = &smem[bufi][idx * 16];
      const int cb = (idx & 3) << 4;
      if (idx < ACH) {
        const int row = idx >> 2;
        const int scb = cb ^ (((row >> 1) & 3) << 4);
        glds16((const char*)A + ((size_t)(m0 + row) * KDIM + k0) * 2 + scb, dst);
      } else {
        const int row = (idx - ACH) >> 2;
        const int scb = cb ^ (((row >> 1) & 3) << 4);
        glds16((const char*)Bw + ((size_t)(n0 + row) * KDIM + k0) * 2 + scb, dst);
      }
    }
  };

  stage(0, 0);
  __syncthreads();

  for (int kb = 0; kb < KDIM / 32; ++kb) {
    const int cur = kb & 1;
    if (kb + 1 < KDIM / 32) stage(cur ^ 1, (kb + 1) * 32);

    const char* Ab = smem[cur];
    const char* Bb = smem[cur] + BM * 64;
    bf16x8 af[4], bfr[NI];
#pragma unroll
    for (int mi = 0; mi < 4; ++mi)
      af[mi] = *(const bf16x8*)(Ab + (wmoff + mi * 16 + r16) * 64 +
                                ((hf << 4) ^ gx));
#pragma unroll
    for (int ni = 0; ni < NI; ++ni)
      bfr[ni] = *(const bf16x8*)(Bb + (wnoff + ni * 16 + r16) * 64 +
                                 ((hf << 4) ^ gx));
#pragma unroll
    for (int mi = 0; mi < 4; ++mi)
#pragma unroll
      for (int ni = 0; ni < NI; ++ni)
        acc[mi][ni] = __builtin_amdgcn_mfma_f32_16x16x32_bf16(af[mi], bfr[ni],
                                                              acc[mi][ni], 0, 0, 0);
    __syncthreads();
  }

  if constexpr (MODE == 0) {
#pragma unroll
    for (int mi = 0; mi < 4; ++mi) {
      const int rowb = m0 + wmoff + (mi << 4) + (hf << 2);
#pragma unroll
      for (int ni = 0; ni < NI; ++ni) {
        const int col = n0 + wnoff + (ni << 4) + r16;
#pragma unroll
        for (int r = 0; r < 4; ++r)
          Cf[(size_t)(rowb + r) * Ncols + col] = acc[mi][ni][r];
      }
    }
  } else {
    const int proj = n0 >> 10;
#pragma unroll
    for (int mi = 0; mi < 4; ++mi) {
      const int rowb = m0 + wmoff + (mi << 4) + (hf << 2);
      const int b = rowb >> 11;  // uniform for r=0..3 (rowb % 4 == 0)
      const int sbase = rowb & 2047;
#pragma unroll
      for (int ni = 0; ni < NI; ++ni) {
        const int col = n0 + wnoff + (ni << 4) + r16;
        const int ecol = col & 1023;
        const int h = ecol >> 6, dk = ecol & 63;
        if (proj < 2) {
#pragma unroll
          for (int r = 0; r < 4; ++r) {
            float v = acc[mi][ni][r];
            const int s = sbase + r;
            float p = __shfl_xor(v, 1, 64);
            const int fi = dk >> 1;
            const float c = cosT[(s << 5) + fi];
            const float sn = sinT[(s << 5) + fi];
            float ov = v * c + ((dk & 1) ? p : -p) * sn;
            if (proj == 0) ov *= QSCALE;  // fold 1/sqrt(dk)*log2e into Q
            __hip_bfloat16* dst = (proj == 0) ? Qr : Kr;
            dst[((size_t)((b << 4) + h) * S + s) * DK + dk] = __float2bfloat16(ov);
          }
        } else {
          // V: k-permuted store; r=0..3 map to consecutive sp -> ushort4
          const int sp0 = (sbase & ~63) | kperm64(sbase & 63);
          union { ushort4 u; __hip_bfloat16 hh[4]; } vp;
#pragma unroll
          for (int r = 0; r < 4; ++r)
            vp.hh[r] = __float2bfloat16(acc[mi][ni][r]);
          *reinterpret_cast<ushort4*>(
              &Vt[((size_t)((b << 4) + h) * DK + dk) * S + sp0]) = vp.u;
        }
      }
    }
  }
}

// ---------------- causal flash attention v5 (balanced triples) ------------
__global__ __launch_bounds__(256) void attn_kernel(
    const __hip_bfloat16* __restrict__ Q,
    const __hip_bfloat16* __restrict__ Kr,
    const __hip_bfloat16* __restrict__ Vp,
    __hip_bfloat16* __restrict__ AO,
    __hip_bfloat16* __restrict__ Opart,  // [bh][16 splits][128][64] bf16
    float* __restrict__ ml) {            // [bh][16 splits][128][2] f32
  __shared__ __attribute__((aligned(16))) __hip_bfloat16 Ks[2][64 * 64];
  __shared__ __attribute__((aligned(16))) __hip_bfloat16 Vs[2][64 * 64];
  static const int T[8][3] = {{0, 1, 23},  {2, 5, 20},  {3, 9, 17}, {4, 15, 14},
                              {6, 16, 21}, {7, 11, 18}, {10, 8, 22}, {12, 13, 19}};
  const int tid = threadIdx.x;
  const int lane = tid & 63, wid = tid >> 6;
  const int r16 = lane & 15, hf = lane >> 4;
  const bool hi32 = (lane >= 32);
  const int bh = blockIdx.x & 31;
  const int cg = (blockIdx.x >> 5) & 7;
  const int slot = blockIdx.x >> 8;
  const int item = T[cg][slot];
  const int g = item / 3, j = item - 3 * g;
  int qt, k0, k1;
  bool dosplit;
  if (j < 2) {
    qt = 15 - g;
    const int nt = (qt << 1) + 2;
    k0 = j ? (nt >> 1) : 0;
    k1 = j ? nt : (nt >> 1);
    dosplit = true;
  } else {
    qt = 7 - g;
    k0 = 0;
    k1 = (qt << 1) + 2;
    dosplit = false;
  }
  const __hip_bfloat16* Qh = Q + (size_t)bh * S * DK;
  const __hip_bfloat16* Kh = Kr + (size_t)bh * S * DK;
  const __hip_bfloat16* Vh = Vp + (size_t)bh * DK * S;

  const int qbase = (qt << 7) + (wid << 5);

  bf16x8 bq[2][2];
#pragma unroll
  for (int qf = 0; qf < 2; ++qf)
#pragma unroll
    for (int ks = 0; ks < 2; ++ks)
      bq[qf][ks] = *(const bf16x8*)(Qh + (size_t)(qbase + (qf << 4) + r16) * DK +
                                    ks * 32 + hf * 8);

  f32x4 o[2][4];
#pragma unroll
  for (int qf = 0; qf < 2; ++qf)
#pragma unroll
    for (int f = 0; f < 4; ++f) o[qf][f] = (f32x4)0.0f;
  float m[2] = {-1e30f, -1e30f}, l[2] = {0.0f, 0.0f};

#define STAGE(bufi, t)                                                         \
  {                                                                            \
    _Pragma("unroll") for (int i = 0; i < 2; ++i) {                            \
      const int idx = i * 256 + tid;                                           \
      const int row = idx >> 3;                                                \
      const int cb = (idx & 7) << 4;                                           \
      const int scb = cb ^ ((row & 7) << 4);                                   \
      glds16((const char*)Kh + ((size_t)(((t) << 6) + row) * DK) * 2 + scb,    \
             (char*)(&Ks[bufi][0]) + idx * 16);                                \
      glds16((const char*)Vh + ((size_t)row * S + ((t) << 6)) * 2 + scb,       \
             (char*)(&Vs[bufi][0]) + idx * 16);                                \
    }                                                                          \
  }

  STAGE(0, k0);
  __syncthreads();

  for (int kt = k0; kt < k1; ++kt) {
    const int cur = (kt - k0) & 1;
    if (kt + 1 < k1) STAGE(cur ^ 1, kt + 1);

    // S^T = K Q^T  (scores already in exp2 domain via pre-scaled Q)
    f32x4 p[2][4];
#pragma unroll
    for (int qf = 0; qf < 2; ++qf)
#pragma unroll
      for (int kf = 0; kf < 4; ++kf) p[qf][kf] = (f32x4)0.0f;
    __builtin_amdgcn_s_setprio(1);
#pragma unroll
    for (int ks = 0; ks < 2; ++ks) {
#pragma unroll
      for (int kf = 0; kf < 4; ++kf) {
        const int krow = (kf << 4) + r16;
        const int cb = (ks << 6) + (hf << 4);
        const bf16x8 ak = *(const bf16x8*)((const char*)(&Ks[cur][0]) +
                                           krow * 128 + (cb ^ ((krow & 7) << 4)));
#pragma unroll
        for (int qf = 0; qf < 2; ++qf)
          p[qf][kf] = __builtin_amdgcn_mfma_f32_16x16x32_bf16(ak, bq[qf][ks],
                                                              p[qf][kf], 0, 0, 0);
      }
    }
    __builtin_amdgcn_s_setprio(0);

    // causal mask (diag tiles only; wave-uniform branch)
    if (kt >= (qt << 1)) {
#pragma unroll
      for (int qf = 0; qf < 2; ++qf) {
        const int qg = qbase + (qf << 4) + r16;
#pragma unroll
        for (int kf = 0; kf < 4; ++kf)
#pragma unroll
          for (int r = 0; r < 4; ++r) {
            const int kg = (kt << 6) + (kf << 4) + (hf << 2) + r;
            if (kg > qg) p[qf][kf][r] = -1e30f;
          }
      }
    }

    // online softmax with defer-max (T13, THR=8 log2-units)
#pragma unroll
    for (int qf = 0; qf < 2; ++qf) {
      f32x4 m4;
#pragma unroll
      for (int e = 0; e < 4; ++e)
        m4[e] = fmaxf(fmaxf(p[qf][0][e], p[qf][1][e]),
                      fmaxf(p[qf][2][e], p[qf][3][e]));
      float t = fmaxf(fmaxf(m4[0], m4[1]), fmaxf(m4[2], m4[3]));
      t = fmaxf(t, __shfl_xor(t, 16, 64));
      t = fmaxf(t, __shfl_xor(t, 32, 64));
      if (t > m[qf] + 8.0f) {  // wave-uniform
        const float scl = fexp2(m[qf] - t);
        m[qf] = t;
        l[qf] *= scl;
#pragma unroll
        for (int f = 0; f < 4; ++f)
#pragma unroll
          for (int r = 0; r < 4; ++r) o[qf][f][r] *= scl;
      }
      float ss = 0.0f;
#pragma unroll
      for (int kf = 0; kf < 4; ++kf)
#pragma unroll
        for (int r = 0; r < 4; ++r) {
          const float e = fexp2(p[qf][kf][r] - m[qf]);
          p[qf][kf][r] = e;
          ss += e;
        }
      ss += __shfl_xor(ss, 16, 64);
      ss += __shfl_xor(ss, 32, 64);
      l[qf] += ss;
    }

    // P -> bf16 frags in-register
    union PW { unsigned u[4]; bf16x8 v; };
    PW pb[2][2];
#pragma unroll
    for (int qf = 0; qf < 2; ++qf) {
      unsigned w[4][2];
#pragma unroll
      for (int kf = 0; kf < 4; ++kf) {
        w[kf][0] = cvtpk(p[qf][kf][0], p[qf][kf][1]);
        w[kf][1] = cvtpk(p[qf][kf][2], p[qf][kf][3]);
      }
#pragma unroll
      for (int ks = 0; ks < 2; ++ks) {
        unsigned a0 = w[2 * ks][0], b0 = w[2 * ks + 1][0];
        unsigned a1 = w[2 * ks][1], b1 = w[2 * ks + 1][1];
        pb[qf][ks].u[0] = hi32 ? b0 : a0;
        pb[qf][ks].u[1] = hi32 ? b1 : a1;
        pl32swap(a0, b0);
        pl32swap(a1, b1);
        pb[qf][ks].u[2] = hi32 ? a0 : b0;
        pb[qf][ks].u[3] = hi32 ? a1 : b1;
      }
    }

    // O^T += V' P
    __builtin_amdgcn_s_setprio(1);
#pragma unroll
    for (int ks = 0; ks < 2; ++ks) {
#pragma unroll
      for (int f = 0; f < 4; ++f) {
        const int vrow = (f << 4) + r16;
        const int cb = (ks << 6) + (hf << 4);
        const bf16x8 av = *(const bf16x8*)((const char*)(&Vs[cur][0]) +
                                           vrow * 128 + (cb ^ ((vrow & 7) << 4)));
#pragma unroll
        for (int qf = 0; qf < 2; ++qf)
          o[qf][f] = __builtin_amdgcn_mfma_f32_16x16x32_bf16(av, pb[qf][ks].v,
                                                             o[qf][f], 0, 0, 0);
      }
    }
    __builtin_amdgcn_s_setprio(0);

    __syncthreads();
  }
#undef STAGE

  if (!dosplit) {
    const int b = bh >> 4, h = bh & 15;
#pragma unroll
    for (int qf = 0; qf < 2; ++qf) {
      const float inv = 1.0f / l[qf];
      const int q = qbase + (qf << 4) + r16;
#pragma unroll
      for (int f = 0; f < 4; ++f)
#pragma unroll
        for (int r = 0; r < 4; ++r) {
          const int dv = (f << 4) + (hf << 2) + r;
          AO[((size_t)b * S + q) * D + (h << 6) + dv] =
              __float2bfloat16(o[qf][f][r] * inv);
        }
    }
  } else {
    const int sidx = (g << 1) | j;
    __hip_bfloat16* op = Opart + (((size_t)bh * 16 + sidx) << 13);
    float* mlp = ml + (((size_t)bh * 16 + sidx) << 8);
#pragma unroll
    for (int qf = 0; qf < 2; ++qf) {
      const float inv = 1.0f / l[qf];
      const int rowin = (wid << 5) + (qf << 4) + r16;
#pragma unroll
      for (int f = 0; f < 4; ++f)
#pragma unroll
        for (int r = 0; r < 4; ++r) {
          const int dv = (f << 4) + (hf << 2) + r;
          op[rowin * 64 + dv] = __float2bfloat16(o[qf][f][r] * inv);
        }
      if (hf == 0) {
        mlp[rowin * 2] = m[qf];
        mlp[rowin * 2 + 1] = l[qf];
      }
    }
  }
}

// ---------------- merge the split partials (m in exp2 domain) -------------
__global__ __launch_bounds__(256) void merge_kernel(
    const __hip_bfloat16* __restrict__ Opart,
    const float* __restrict__ ml,
    __hip_bfloat16* __restrict__ AO) {
  const int rg = blockIdx.x * 256 + threadIdx.x;  // 32768 rows
  const int bh = rg >> 10;
  const int rem = rg & 1023;
  const int gq = rem >> 7;  // 0..7 -> qt = 15-gq
  const int rowin = rem & 127;
  const int s0 = bh * 16 + (gq << 1), s1 = s0 + 1;
  const float m0 = ml[(s0 << 8) + rowin * 2], l0 = ml[(s0 << 8) + rowin * 2 + 1];
  const float m1 = ml[(s1 << 8) + rowin * 2], l1 = ml[(s1 << 8) + rowin * 2 + 1];
  const float mx = fmaxf(m0, m1);
  float w0 = l0 * fexp2(m0 - mx), w1 = l1 * fexp2(m1 - mx);
  const float inv = 1.0f / (w0 + w1);
  w0 *= inv;
  w1 *= inv;
  const bf16x8* p0 = (const bf16x8*)(Opart + (((size_t)s0) << 13) + rowin * 64);
  const bf16x8* p1 = (const bf16x8*)(Opart + (((size_t)s1) << 13) + rowin * 64);
  const int b = bh >> 4, h = bh & 15;
  const int q = ((15 - gq) << 7) + rowin;
  bf16x8* dst = (bf16x8*)(AO + ((size_t)b * S + q) * D + (h << 6));
#pragma unroll
  for (int i = 0; i < 8; ++i) {
    bf16x8 a = p0[i], c = p1[i];
    bf16x8 r;
#pragma unroll
    for (int e = 0; e < 8; ++e)
      r[e] = (__bf16)(w0 * (float)a[e] + w1 * (float)c[e]);
    dst[i] = r;
  }
}

extern "C" void kernel_launch(void* const* d_in, const int* in_sizes, int n_in,
                              void* d_out, int out_size, void* d_ws, size_t ws_size,
                              hipStream_t stream) {
  (void)in_sizes; (void)n_in; (void)out_size; (void)ws_size;
  const float* x  = (const float*)d_in[0];
  const float* Wq = (const float*)d_in[1];
  const float* Wk = (const float*)d_in[2];
  const float* Wv = (const float*)d_in[3];
  const float* Wo = (const float*)d_in[4];
  float* out = (float*)d_out;
  char* ws = (char*)d_ws;
  const size_t MB = (size_t)1 << 20;
  __hip_bfloat16* xb   = (__hip_bfloat16*)(ws);             //  8 MB (dead after gemm1)
  __hip_bfloat16* Wcat = (__hip_bfloat16*)(ws + 8 * MB);    //  6 MB (dead after gemm1)
  __hip_bfloat16* Wob  = (__hip_bfloat16*)(ws + 14 * MB);   //  2 MB (live till gemm0)
  __hip_bfloat16* Qr   = (__hip_bfloat16*)(ws + 16 * MB);   //  8 MB (pre-scaled)
  __hip_bfloat16* Kr   = (__hip_bfloat16*)(ws + 24 * MB);   //  8 MB
  __hip_bfloat16* Vt   = (__hip_bfloat16*)(ws + 32 * MB);   //  8 MB (k-permuted)
  __hip_bfloat16* AO   = (__hip_bfloat16*)(ws + 40 * MB);   //  8 MB
  float* cosT = (float*)(ws + 48 * MB);                     // 256 KB
  float* sinT = (float*)(ws + 48 * MB + 256 * 1024);        // 256 KB
  __hip_bfloat16* Opart = (__hip_bfloat16*)(ws);            //  8 MB (reuse xb)
  float* mlbuf = (float*)(ws + 8 * MB);                     //  512 KB (reuse Wcat)

  pre_kernel<<<8448, 256, 0, stream>>>(x, Wq, Wk, Wv, Wo, xb, Wcat, Wob,
                                       cosT, sinT);
  // QKV projection + RoPE + scatter: 128x128 tile, 768 blocks (3/CU)
  gemm_nt_kernel<1, 128, 128><<<(4096 / 128) * (3072 / 128), 256, 0, stream>>>(
      xb, Wcat, nullptr, Qr, Kr, Vt, cosT, sinT, 3072);
  attn_kernel<<<32 * 24, 256, 0, stream>>>(Qr, Kr, Vt, AO, Opart, mlbuf);
  merge_kernel<<<128, 256, 0, stream>>>(Opart, mlbuf, AO);
  // output projection: 64x128 tile, 512 blocks (2/CU)
  gemm_nt_kernel<0, 64, 128><<<(4096 / 64) * (1024 / 128), 256, 0, stream>>>(
      AO, Wob, out, nullptr, nullptr, nullptr, nullptr, nullptr, 1024);
}

// Round 8
// 190.896 us; speedup vs baseline: 1.1882x; 1.0015x over previous
//
#include <hip/hip_runtime.h>
#include <hip/hip_bf16.h>

typedef float f32x4 __attribute__((ext_vector_type(4)));
typedef __bf16 bf16x8 __attribute__((ext_vector_type(8)));

static constexpr int S  = 2048;
static constexpr int D  = 1024;
static constexpr int DK = 64;
static constexpr int KDIM = 1024;
// 0.125 (1/sqrt(dk)) * log2(e): folded into Q so QK^T lands in exp2 domain
static constexpr float QSCALE = 0.18033688f;

#define AS1 __attribute__((address_space(1)))
#define AS3 __attribute__((address_space(3)))

__device__ __forceinline__ void glds16(const void* g, void* l) {
  __builtin_amdgcn_global_load_lds((const AS1 void*)g, (AS3 void*)l, 16, 0, 0);
}

__device__ __forceinline__ unsigned cvtpk(float lo, float hi) {
  unsigned r;
  asm("v_cvt_pk_bf16_f32 %0, %1, %2" : "=v"(r) : "v"(lo), "v"(hi));
  return r;
}

__device__ __forceinline__ void pl32swap(unsigned& a, unsigned& b) {
  asm("v_permlane32_swap_b32 %0, %1" : "+v"(a), "+v"(b));
}

__device__ __forceinline__ float fexp2(float x) {
  float r;
  asm("v_exp_f32 %0, %1" : "=v"(r) : "v"(x));
  return r;
}

// counted-vmcnt barrier (T4): wait for all but the newest stage's N loads,
// then raw barrier. Never drains the in-flight prefetch to 0 in steady state.
template <int N>
__device__ __forceinline__ void pipe_barrier(bool last) {
  if (!last) {
    if constexpr (N == 4) asm volatile("s_waitcnt vmcnt(4)" ::: "memory");
    else if constexpr (N == 3) asm volatile("s_waitcnt vmcnt(3)" ::: "memory");
    else asm volatile("s_waitcnt vmcnt(0)" ::: "memory");
  } else {
    asm volatile("s_waitcnt vmcnt(0)" ::: "memory");
  }
  __builtin_amdgcn_s_barrier();
  __builtin_amdgcn_sched_barrier(0);
}

// k-permutation within a 64 block (bijective); maps r=0..3 (k aligned 4) to
// consecutive outputs, enabling vectorized V^T stores.
__device__ __forceinline__ int kperm64(int k) {
  const int kf = k >> 4, hs = (k >> 2) & 3, r = k & 3;
  const bool inl = ((kf & 1) == (hs >> 1));
  const int h = inl ? hs : (hs ^ 2);
  const int j = inl ? r : (r + 4);
  return ((kf >> 1) << 5) + (h << 3) + j;
}

// ---------------- fused pre-pass: all f32->bf16 cvt + RoPE tables ----------
__global__ __launch_bounds__(256) void pre_kernel(
    const float* __restrict__ x,  const float* __restrict__ Wq,
    const float* __restrict__ Wk, const float* __restrict__ Wv,
    const float* __restrict__ Wo,
    __hip_bfloat16* __restrict__ xb, __hip_bfloat16* __restrict__ Wcat,
    __hip_bfloat16* __restrict__ Wob,
    float* __restrict__ cosT, float* __restrict__ sinT) {
  const int gid = blockIdx.x * 256 + threadIdx.x;
  if (gid < 2097152) {
    const float* src;
    __hip_bfloat16* dst;
    int off;
    if (gid < 1048576)      { src = x;  dst = xb;             off = gid; }
    else if (gid < 1310720) { src = Wq; dst = Wcat;           off = gid - 1048576; }
    else if (gid < 1572864) { src = Wk; dst = Wcat + 1048576; off = gid - 1310720; }
    else if (gid < 1835008) { src = Wv; dst = Wcat + 2097152; off = gid - 1572864; }
    else                    { src = Wo; dst = Wob;            off = gid - 1835008; }
    float4 v = reinterpret_cast<const float4*>(src)[off];
    union { ushort4 u; __hip_bfloat16 h[4]; } o;
    o.h[0] = __float2bfloat16(v.x);
    o.h[1] = __float2bfloat16(v.y);
    o.h[2] = __float2bfloat16(v.z);
    o.h[3] = __float2bfloat16(v.w);
    reinterpret_cast<ushort4*>(dst)[off] = o.u;
  } else {
    const int idx = gid - 2097152;  // S*32
    const int s = idx >> 5, fi = idx & 31;
    float invf = powf(10000.0f, -(float)(2 * fi) / 64.0f);
    float ang = (float)s * invf;
    cosT[idx] = cosf(ang);
    sinT[idx] = sinf(ang);
  }
}

// ---------------- NT GEMM v4: quad-swizzle + 3-buffer counted pipeline ----
// Row-major LDS [row][64B], 16B chunks XOR-permuted by ((row>>1)&3) on both
// sides (rule #21). 3 buffers, prefetch distance 2, counted vmcnt (T4):
// the newest stage stays in flight across the barrier.
template <int MODE, int BM, int BN>
__global__ __launch_bounds__(256) void gemm_nt_kernel(
    const __hip_bfloat16* __restrict__ A,
    const __hip_bfloat16* __restrict__ Bw,
    float* __restrict__ Cf,
    __hip_bfloat16* __restrict__ Qr,
    __hip_bfloat16* __restrict__ Kr,
    __hip_bfloat16* __restrict__ Vt,
    const float* __restrict__ cosT,
    const float* __restrict__ sinT,
    int Ncols) {
  constexpr int NI = (BM == 128) ? 4 : 2;  // n-frags per wave
  constexpr int ACH = BM * 4;              // 16B chunks in A tile
  constexpr int TCH = (BM + BN) * 4;
  constexpr int NLD = TCH / 256;           // glds16 per thread per stage
  constexpr int NK = KDIM / 32;
  __shared__ __attribute__((aligned(16))) char smem[3][(BM + BN) * 64];
  const int tid = threadIdx.x;
  const int nbn = Ncols / BN;
  const int cpx = gridDim.x >> 3;
  const int swz = (blockIdx.x & 7) * cpx + (blockIdx.x >> 3);
  const int bm = swz / nbn;
  const int bn = swz % nbn;
  const int m0 = bm * BM, n0 = bn * BN;
  const int lane = tid & 63;
  const int wid = tid >> 6;
  const int r16 = lane & 15, hf = lane >> 4;
  const int wmoff = (BM == 128) ? ((wid >> 1) << 6) : 0;
  const int wnoff = (BM == 128) ? ((wid & 1) << 6) : (wid << 5);
  const int gx = ((r16 >> 1) & 3) << 4;  // quad-swizzle for fragment reads

  f32x4 acc[4][NI];
#pragma unroll
  for (int i = 0; i < 4; ++i)
#pragma unroll
    for (int j = 0; j < NI; ++j) acc[i][j] = (f32x4)0.0f;

  auto stage = [&](int bufi, int k0) {
#pragma unroll
    for (int i = 0; i < NLD; ++i) {
      const int idx = i * 256 + tid;
      char* dst = &smem[bufi][idx * 16];
      const int cb = (idx & 3) << 4;
      if (idx < ACH) {
        const int row = idx >> 2;
        const int scb = cb ^ (((row >> 1) & 3) << 4);
        glds16((const char*)A + ((size_t)(m0 + row) * KDIM + k0) * 2 + scb, dst);
      } else {
        const int row = (idx - ACH) >> 2;
        const int scb = cb ^ (((row >> 1) & 3) << 4);
        glds16((const char*)Bw + ((size_t)(n0 + row) * KDIM + k0) * 2 + scb, dst);
      }
    }
  };

  stage(0, 0);
  stage(1, 32);

  for (int kb = 0; kb < NK; ++kb) {
    const int bi = kb % 3;
    pipe_barrier<NLD>(kb + 1 >= NK);
    if (kb + 2 < NK) stage((kb + 2) % 3, (kb + 2) * 32);

    const char* Ab = smem[bi];
    const char* Bb = smem[bi] + BM * 64;
    bf16x8 af[4], bfr[NI];
#pragma unroll
    for (int mi = 0; mi < 4; ++mi)
      af[mi] = *(const bf16x8*)(Ab + (wmoff + mi * 16 + r16) * 64 +
                                ((hf << 4) ^ gx));
#pragma unroll
    for (int ni = 0; ni < NI; ++ni)
      bfr[ni] = *(const bf16x8*)(Bb + (wnoff + ni * 16 + r16) * 64 +
                                 ((hf << 4) ^ gx));
#pragma unroll
    for (int mi = 0; mi < 4; ++mi)
#pragma unroll
      for (int ni = 0; ni < NI; ++ni)
        acc[mi][ni] = __builtin_amdgcn_mfma_f32_16x16x32_bf16(af[mi], bfr[ni],
                                                              acc[mi][ni], 0, 0, 0);
  }

  if constexpr (MODE == 0) {
#pragma unroll
    for (int mi = 0; mi < 4; ++mi) {
      const int rowb = m0 + wmoff + (mi << 4) + (hf << 2);
#pragma unroll
      for (int ni = 0; ni < NI; ++ni) {
        const int col = n0 + wnoff + (ni << 4) + r16;
#pragma unroll
        for (int r = 0; r < 4; ++r)
          Cf[(size_t)(rowb + r) * Ncols + col] = acc[mi][ni][r];
      }
    }
  } else {
    const int proj = n0 >> 10;
#pragma unroll
    for (int mi = 0; mi < 4; ++mi) {
      const int rowb = m0 + wmoff + (mi << 4) + (hf << 2);
      const int b = rowb >> 11;  // uniform for r=0..3 (rowb % 4 == 0)
      const int sbase = rowb & 2047;
#pragma unroll
      for (int ni = 0; ni < NI; ++ni) {
        const int col = n0 + wnoff + (ni << 4) + r16;
        const int ecol = col & 1023;
        const int h = ecol >> 6, dk = ecol & 63;
        if (proj < 2) {
#pragma unroll
          for (int r = 0; r < 4; ++r) {
            float v = acc[mi][ni][r];
            const int s = sbase + r;
            float p = __shfl_xor(v, 1, 64);
            const int fi = dk >> 1;
            const float c = cosT[(s << 5) + fi];
            const float sn = sinT[(s << 5) + fi];
            float ov = v * c + ((dk & 1) ? p : -p) * sn;
            if (proj == 0) ov *= QSCALE;  // fold 1/sqrt(dk)*log2e into Q
            __hip_bfloat16* dst = (proj == 0) ? Qr : Kr;
            dst[((size_t)((b << 4) + h) * S + s) * DK + dk] = __float2bfloat16(ov);
          }
        } else {
          // V: k-permuted store; r=0..3 map to consecutive sp -> ushort4
          const int sp0 = (sbase & ~63) | kperm64(sbase & 63);
          union { ushort4 u; __hip_bfloat16 hh[4]; } vp;
#pragma unroll
          for (int r = 0; r < 4; ++r)
            vp.hh[r] = __float2bfloat16(acc[mi][ni][r]);
          *reinterpret_cast<ushort4*>(
              &Vt[((size_t)((b << 4) + h) * DK + dk) * S + sp0]) = vp.u;
        }
      }
    }
  }
}

// ---------------- causal flash attention v6 (3-buffer counted pipeline) ---
__global__ __launch_bounds__(256) void attn_kernel(
    const __hip_bfloat16* __restrict__ Q,
    const __hip_bfloat16* __restrict__ Kr,
    const __hip_bfloat16* __restrict__ Vp,
    __hip_bfloat16* __restrict__ AO,
    __hip_bfloat16* __restrict__ Opart,  // [bh][16 splits][128][64] bf16
    float* __restrict__ ml) {            // [bh][16 splits][128][2] f32
  __shared__ __attribute__((aligned(16))) __hip_bfloat16 Ks[3][64 * 64];
  __shared__ __attribute__((aligned(16))) __hip_bfloat16 Vs[3][64 * 64];
  static const int T[8][3] = {{0, 1, 23},  {2, 5, 20},  {3, 9, 17}, {4, 15, 14},
                              {6, 16, 21}, {7, 11, 18}, {10, 8, 22}, {12, 13, 19}};
  const int tid = threadIdx.x;
  const int lane = tid & 63, wid = tid >> 6;
  const int r16 = lane & 15, hf = lane >> 4;
  const bool hi32 = (lane >= 32);
  const int bh = blockIdx.x & 31;
  const int cg = (blockIdx.x >> 5) & 7;
  const int slot = blockIdx.x >> 8;
  const int item = T[cg][slot];
  const int g = item / 3, j = item - 3 * g;
  int qt, k0, k1;
  bool dosplit;
  if (j < 2) {
    qt = 15 - g;
    const int nt = (qt << 1) + 2;
    k0 = j ? (nt >> 1) : 0;
    k1 = j ? nt : (nt >> 1);
    dosplit = true;
  } else {
    qt = 7 - g;
    k0 = 0;
    k1 = (qt << 1) + 2;
    dosplit = false;
  }
  const __hip_bfloat16* Qh = Q + (size_t)bh * S * DK;
  const __hip_bfloat16* Kh = Kr + (size_t)bh * S * DK;
  const __hip_bfloat16* Vh = Vp + (size_t)bh * DK * S;

  const int qbase = (qt << 7) + (wid << 5);

  bf16x8 bq[2][2];
#pragma unroll
  for (int qf = 0; qf < 2; ++qf)
#pragma unroll
    for (int ks = 0; ks < 2; ++ks)
      bq[qf][ks] = *(const bf16x8*)(Qh + (size_t)(qbase + (qf << 4) + r16) * DK +
                                    ks * 32 + hf * 8);

  f32x4 o[2][4];
#pragma unroll
  for (int qf = 0; qf < 2; ++qf)
#pragma unroll
    for (int f = 0; f < 4; ++f) o[qf][f] = (f32x4)0.0f;
  float m[2] = {-1e30f, -1e30f}, l[2] = {0.0f, 0.0f};

#define STAGE(bufi, t)                                                         \
  {                                                                            \
    _Pragma("unroll") for (int i = 0; i < 2; ++i) {                            \
      const int idx = i * 256 + tid;                                           \
      const int row = idx >> 3;                                                \
      const int cb = (idx & 7) << 4;                                           \
      const int scb = cb ^ ((row & 7) << 4);                                   \
      glds16((const char*)Kh + ((size_t)(((t) << 6) + row) * DK) * 2 + scb,    \
             (char*)(&Ks[bufi][0]) + idx * 16);                                \
      glds16((const char*)Vh + ((size_t)row * S + ((t) << 6)) * 2 + scb,       \
             (char*)(&Vs[bufi][0]) + idx * 16);                                \
    }                                                                          \
  }

  STAGE(0, k0);
  STAGE(1, k0 + 1);  // k1-k0 >= 2 always

  for (int kt = k0; kt < k1; ++kt) {
    const int bi = (kt - k0) % 3;
    pipe_barrier<4>(kt + 1 >= k1);
    if (kt + 2 < k1) STAGE((kt - k0 + 2) % 3, kt + 2);

    // S^T = K Q^T  (scores already in exp2 domain via pre-scaled Q)
    f32x4 p[2][4];
#pragma unroll
    for (int qf = 0; qf < 2; ++qf)
#pragma unroll
      for (int kf = 0; kf < 4; ++kf) p[qf][kf] = (f32x4)0.0f;
    __builtin_amdgcn_s_setprio(1);
#pragma unroll
    for (int ks = 0; ks < 2; ++ks) {
#pragma unroll
      for (int kf = 0; kf < 4; ++kf) {
        const int krow = (kf << 4) + r16;
        const int cb = (ks << 6) + (hf << 4);
        const bf16x8 ak = *(const bf16x8*)((const char*)(&Ks[bi][0]) +
                                           krow * 128 + (cb ^ ((krow & 7) << 4)));
#pragma unroll
        for (int qf = 0; qf < 2; ++qf)
          p[qf][kf] = __builtin_amdgcn_mfma_f32_16x16x32_bf16(ak, bq[qf][ks],
                                                              p[qf][kf], 0, 0, 0);
      }
    }
    __builtin_amdgcn_s_setprio(0);

    // causal mask (diag tiles only; wave-uniform branch)
    if (kt >= (qt << 1)) {
#pragma unroll
      for (int qf = 0; qf < 2; ++qf) {
        const int qg = qbase + (qf << 4) + r16;
#pragma unroll
        for (int kf = 0; kf < 4; ++kf)
#pragma unroll
          for (int r = 0; r < 4; ++r) {
            const int kg = (kt << 6) + (kf << 4) + (hf << 2) + r;
            if (kg > qg) p[qf][kf][r] = -1e30f;
          }
      }
    }

    // online softmax with defer-max (T13, THR=8 log2-units)
#pragma unroll
    for (int qf = 0; qf < 2; ++qf) {
      f32x4 m4;
#pragma unroll
      for (int e = 0; e < 4; ++e)
        m4[e] = fmaxf(fmaxf(p[qf][0][e], p[qf][1][e]),
                      fmaxf(p[qf][2][e], p[qf][3][e]));
      float t = fmaxf(fmaxf(m4[0], m4[1]), fmaxf(m4[2], m4[3]));
      t = fmaxf(t, __shfl_xor(t, 16, 64));
      t = fmaxf(t, __shfl_xor(t, 32, 64));
      if (t > m[qf] + 8.0f) {  // wave-uniform
        const float scl = fexp2(m[qf] - t);
        m[qf] = t;
        l[qf] *= scl;
#pragma unroll
        for (int f = 0; f < 4; ++f)
#pragma unroll
          for (int r = 0; r < 4; ++r) o[qf][f][r] *= scl;
      }
      float ss = 0.0f;
#pragma unroll
      for (int kf = 0; kf < 4; ++kf)
#pragma unroll
        for (int r = 0; r < 4; ++r) {
          const float e = fexp2(p[qf][kf][r] - m[qf]);
          p[qf][kf][r] = e;
          ss += e;
        }
      ss += __shfl_xor(ss, 16, 64);
      ss += __shfl_xor(ss, 32, 64);
      l[qf] += ss;
    }

    // P -> bf16 frags in-register
    union PW { unsigned u[4]; bf16x8 v; };
    PW pb[2][2];
#pragma unroll
    for (int qf = 0; qf < 2; ++qf) {
      unsigned w[4][2];
#pragma unroll
      for (int kf = 0; kf < 4; ++kf) {
        w[kf][0] = cvtpk(p[qf][kf][0], p[qf][kf][1]);
        w[kf][1] = cvtpk(p[qf][kf][2], p[qf][kf][3]);
      }
#pragma unroll
      for (int ks = 0; ks < 2; ++ks) {
        unsigned a0 = w[2 * ks][0], b0 = w[2 * ks + 1][0];
        unsigned a1 = w[2 * ks][1], b1 = w[2 * ks + 1][1];
        pb[qf][ks].u[0] = hi32 ? b0 : a0;
        pb[qf][ks].u[1] = hi32 ? b1 : a1;
        pl32swap(a0, b0);
        pl32swap(a1, b1);
        pb[qf][ks].u[2] = hi32 ? a0 : b0;
        pb[qf][ks].u[3] = hi32 ? a1 : b1;
      }
    }

    // O^T += V' P
    __builtin_amdgcn_s_setprio(1);
#pragma unroll
    for (int ks = 0; ks < 2; ++ks) {
#pragma unroll
      for (int f = 0; f < 4; ++f) {
        const int vrow = (f << 4) + r16;
        const int cb = (ks << 6) + (hf << 4);
        const bf16x8 av = *(const bf16x8*)((const char*)(&Vs[bi][0]) +
                                           vrow * 128 + (cb ^ ((vrow & 7) << 4)));
#pragma unroll
        for (int qf = 0; qf < 2; ++qf)
          o[qf][f] = __builtin_amdgcn_mfma_f32_16x16x32_bf16(av, pb[qf][ks].v,
                                                             o[qf][f], 0, 0, 0);
      }
    }
    __builtin_amdgcn_s_setprio(0);
  }
#undef STAGE

  if (!dosplit) {
    const int b = bh >> 4, h = bh & 15;
#pragma unroll
    for (int qf = 0; qf < 2; ++qf) {
      const float inv = 1.0f / l[qf];
      const int q = qbase + (qf << 4) + r16;
#pragma unroll
      for (int f = 0; f < 4; ++f)
#pragma unroll
        for (int r = 0; r < 4; ++r) {
          const int dv = (f << 4) + (hf << 2) + r;
          AO[((size_t)b * S + q) * D + (h << 6) + dv] =
              __float2bfloat16(o[qf][f][r] * inv);
        }
    }
  } else {
    const int sidx = (g << 1) | j;
    __hip_bfloat16* op = Opart + (((size_t)bh * 16 + sidx) << 13);
    float* mlp = ml + (((size_t)bh * 16 + sidx) << 8);
#pragma unroll
    for (int qf = 0; qf < 2; ++qf) {
      const float inv = 1.0f / l[qf];
      const int rowin = (wid << 5) + (qf << 4) + r16;
#pragma unroll
      for (int f = 0; f < 4; ++f)
#pragma unroll
        for (int r = 0; r < 4; ++r) {
          const int dv = (f << 4) + (hf << 2) + r;
          op[rowin * 64 + dv] = __float2bfloat16(o[qf][f][r] * inv);
        }
      if (hf == 0) {
        mlp[rowin * 2] = m[qf];
        mlp[rowin * 2 + 1] = l[qf];
      }
    }
  }
}

// ---------------- merge the split partials (m in exp2 domain) -------------
__global__ __launch_bounds__(256) void merge_kernel(
    const __hip_bfloat16* __restrict__ Opart,
    const float* __restrict__ ml,
    __hip_bfloat16* __restrict__ AO) {
  const int rg = blockIdx.x * 256 + threadIdx.x;  // 32768 rows
  const int bh = rg >> 10;
  const int rem = rg & 1023;
  const int gq = rem >> 7;  // 0..7 -> qt = 15-gq
  const int rowin = rem & 127;
  const int s0 = bh * 16 + (gq << 1), s1 = s0 + 1;
  const float m0 = ml[(s0 << 8) + rowin * 2], l0 = ml[(s0 << 8) + rowin * 2 + 1];
  const float m1 = ml[(s1 << 8) + rowin * 2], l1 = ml[(s1 << 8) + rowin * 2 + 1];
  const float mx = fmaxf(m0, m1);
  float w0 = l0 * fexp2(m0 - mx), w1 = l1 * fexp2(m1 - mx);
  const float inv = 1.0f / (w0 + w1);
  w0 *= inv;
  w1 *= inv;
  const bf16x8* p0 = (const bf16x8*)(Opart + (((size_t)s0) << 13) + rowin * 64);
  const bf16x8* p1 = (const bf16x8*)(Opart + (((size_t)s1) << 13) + rowin * 64);
  const int b = bh >> 4, h = bh & 15;
  const int q = ((15 - gq) << 7) + rowin;
  bf16x8* dst = (bf16x8*)(AO + ((size_t)b * S + q) * D + (h << 6));
#pragma unroll
  for (int i = 0; i < 8; ++i) {
    bf16x8 a = p0[i], c = p1[i];
    bf16x8 r;
#pragma unroll
    for (int e = 0; e < 8; ++e)
      r[e] = (__bf16)(w0 * (float)a[e] + w1 * (float)c[e]);
    dst[i] = r;
  }
}

extern "C" void kernel_launch(void* const* d_in, const int* in_sizes, int n_in,
                              void* d_out, int out_size, void* d_ws, size_t ws_size,
                              hipStream_t stream) {
  (void)in_sizes; (void)n_in; (void)out_size; (void)ws_size;
  const float* x  = (const float*)d_in[0];
  const float* Wq = (const float*)d_in[1];
  const float* Wk = (const float*)d_in[2];
  const float* Wv = (const float*)d_in[3];
  const float* Wo = (const float*)d_in[4];
  float* out = (float*)d_out;
  char* ws = (char*)d_ws;
  const size_t MB = (size_t)1 << 20;
  __hip_bfloat16* xb   = (__hip_bfloat16*)(ws);             //  8 MB (dead after gemm1)
  __hip_bfloat16* Wcat = (__hip_bfloat16*)(ws + 8 * MB);    //  6 MB (dead after gemm1)
  __hip_bfloat16* Wob  = (__hip_bfloat16*)(ws + 14 * MB);   //  2 MB (live till gemm0)
  __hip_bfloat16* Qr   = (__hip_bfloat16*)(ws + 16 * MB);   //  8 MB (pre-scaled)
  __hip_bfloat16* Kr   = (__hip_bfloat16*)(ws + 24 * MB);   //  8 MB
  __hip_bfloat16* Vt   = (__hip_bfloat16*)(ws + 32 * MB);   //  8 MB (k-permuted)
  __hip_bfloat16* AO   = (__hip_bfloat16*)(ws + 40 * MB);   //  8 MB
  float* cosT = (float*)(ws + 48 * MB);                     // 256 KB
  float* sinT = (float*)(ws + 48 * MB + 256 * 1024);        // 256 KB
  __hip_bfloat16* Opart = (__hip_bfloat16*)(ws);            //  8 MB (reuse xb)
  float* mlbuf = (float*)(ws + 8 * MB);                     //  512 KB (reuse Wcat)

  pre_kernel<<<8448, 256, 0, stream>>>(x, Wq, Wk, Wv, Wo, xb, Wcat, Wob,
                                       cosT, sinT);
  // QKV projection + RoPE + scatter: 128x128 tile, 768 blocks (3/CU)
  gemm_nt_kernel<1, 128, 128><<<(4096 / 128) * (3072 / 128), 256, 0, stream>>>(
      xb, Wcat, nullptr, Qr, Kr, Vt, cosT, sinT, 3072);
  attn_kernel<<<32 * 24, 256, 0, stream>>>(Qr, Kr, Vt, AO, Opart, mlbuf);
  merge_kernel<<<128, 256, 0, stream>>>(Opart, mlbuf, AO);
  // output projection: 64x128 tile, 512 blocks (2/CU)
  gemm_nt_kernel<0, 64, 128><<<(4096 / 64) * (1024 / 128), 256, 0, stream>>>(
      AO, Wob, out, nullptr, nullptr, nullptr, nullptr, nullptr, 1024);
}